// Round 17
// baseline (63.199 us; speedup 1.0000x reference)
//
#include <hip/hip_runtime.h>
#include <math.h>

#define NN 4096
#define FF 128
#define DD 64
#define HH 4
#define NC 256   // HH*DD output columns
#define TSCALE 0.125f   // 2^-3 per table; P scaled 2^-6, cancels in num/den

typedef _Float16 f16x8 __attribute__((ext_vector_type(8)));
typedef _Float16 f16x4 __attribute__((ext_vector_type(4)));
typedef _Float16 f16x2 __attribute__((ext_vector_type(2)));
typedef float    f32x4 __attribute__((ext_vector_type(4)));

// Barrier that does NOT drain vmcnt: LDS visibility only. In-flight global
// loads legally cross it (T4 counted-wait principle; __syncthreads would
// emit s_waitcnt vmcnt(0) and expose full HBM latency every chunk).
#define LDS_BARRIER() asm volatile("s_waitcnt lgkmcnt(0)\n\ts_barrier" ::: "memory")

// ---------------------------------------------------------------------------
// Kernel 1: h = features @ W[h] via f16 LDS staging + v_dot2_f32_f16.
// Emits Bpack (f16 MFMA-B-fragment-ordered chunks) and SCALED f16 exp tables
// Es,Fs,En,Fn ([h][n], each x2^-3).
// ---------------------------------------------------------------------------
__global__ __launch_bounds__(256) void prep_kernel(
    const float* __restrict__ feats, const float* __restrict__ W,
    const float* __restrict__ ak, _Float16* __restrict__ Bpack,
    _Float16* __restrict__ Es, _Float16* __restrict__ Fs,
    _Float16* __restrict__ En, _Float16* __restrict__ Fn)
{
    __shared__ _Float16 Wth[64 * 136];
    __shared__ _Float16 fth[32 * 128];
    __shared__ float    hlds[32 * 65];
    const int t  = threadIdx.x;
    const int h  = blockIdx.y;
    const int n0 = blockIdx.x * 32;

    {
        const float* Wh = W + h * (FF * DD);
        #pragma unroll
        for (int j = 0; j < 8; ++j) {
            int idx = j * 256 + t;
            int f   = idx >> 4;
            int d4  = idx & 15;
            float4 v = ((const float4*)Wh)[idx];
            Wth[(d4 * 4 + 0) * 136 + f] = (_Float16)v.x;
            Wth[(d4 * 4 + 1) * 136 + f] = (_Float16)v.y;
            Wth[(d4 * 4 + 2) * 136 + f] = (_Float16)v.z;
            Wth[(d4 * 4 + 3) * 136 + f] = (_Float16)v.w;
        }
        #pragma unroll
        for (int j = 0; j < 4; ++j) {
            int idx = j * 256 + t;
            int r = idx >> 5, f4 = idx & 31;
            float4 v = ((const float4*)feats)[(size_t)(n0 + r) * 32 + f4];
            f16x4 hv = {(_Float16)v.x, (_Float16)v.y, (_Float16)v.z, (_Float16)v.w};
            *(f16x4*)&fth[r * 128 + f4 * 4] = hv;
        }
    }
    __syncthreads();

    const int d   = t & 63;
    const int wid = t >> 6;
    float acc[8];
    #pragma unroll
    for (int j = 0; j < 8; ++j) acc[j] = 0.f;

    union UW { f16x8 v; unsigned int u[4]; };
    for (int f8 = 0; f8 < 16; ++f8) {
        UW w8; w8.v = *(const f16x8*)&Wth[d * 136 + f8 * 8];
        #pragma unroll
        for (int j = 0; j < 8; ++j) {
            const int r = wid + 4 * j;
            UW fv; fv.v = *(const f16x8*)&fth[r * 128 + f8 * 8];
            #pragma unroll
            for (int p = 0; p < 4; ++p)
                acc[j] = __builtin_amdgcn_fdot2(
                    __builtin_bit_cast(f16x2, w8.u[p]),
                    __builtin_bit_cast(f16x2, fv.u[p]), acc[j], false);
        }
    }

    const float aks = ak[h * 128 + d];
    const float akn = ak[h * 128 + 64 + d];
    #pragma unroll
    for (int j = 0; j < 8; ++j) {
        const int r = wid + 4 * j;
        const float hv = acc[j];
        hlds[r * 65 + d] = hv;
        float v1 = hv * aks;
        float v2 = hv * akn;
        #pragma unroll
        for (int m = 32; m >= 1; m >>= 1) {
            v1 += __shfl_xor(v1, m, 64);
            v2 += __shfl_xor(v2, m, 64);
        }
        if (d == 0) {
            Es[h * NN + n0 + r] = (_Float16)(__expf(v1) * TSCALE);
            Fs[h * NN + n0 + r] = (_Float16)(__expf(0.2f * v1) * TSCALE);
            En[h * NN + n0 + r] = (_Float16)(__expf(v2) * TSCALE);
            Fn[h * NN + n0 + r] = (_Float16)(__expf(0.2f * v2) * TSCALE);
        }
    }
    __syncthreads();

    const int cb = t >> 6;
    const int l  = t & 63;
    const int lr = l & 15;
    const int kg = l >> 4;
    f16x8 v;
    #pragma unroll
    for (int j = 0; j < 8; ++j)
        v[j] = (_Float16)hlds[(kg * 8 + j) * 65 + cb * 16 + lr];
    *(f16x8*)(Bpack + ((size_t)(h * 128 + blockIdx.x)) * 2048 + (cb * 64 + l) * 8) = v;
}

// ---------------------------------------------------------------------------
// Kernel 2: fused MFMA attention == R14 EXACTLY, except the per-chunk
// __syncthreads() is replaced by LDS_BARRIER() (lgkmcnt-only). Adj loads
// for pair k+2 now stay in flight across ~2 iterations (>HBM latency).
// Block = 4 waves = 4 heads sharing rows n0..n0+31; adj read once.
// Depth-2 adj register pipeline; B/tables 1-chunk-ahead named double-buffer;
// chunk rotation; f16 partial outputs (tables pre-scaled).
// ---------------------------------------------------------------------------
__global__ __launch_bounds__(256, 4) void attn_kernel(
    const int* __restrict__ adj, const _Float16* __restrict__ Bpack,
    const _Float16* __restrict__ Es, const _Float16* __restrict__ Fs,
    const _Float16* __restrict__ En, const _Float16* __restrict__ Fn,
    _Float16* __restrict__ pacc, _Float16* __restrict__ pden, int ksplit)
{
    __shared__ _Float16 adjh[2][2][1024];   // [pairbuf][sub][32r x 32m] = 8KB

    const int t  = threadIdx.x;
    const int h  = t >> 6;                  // wave = head
    const int l  = t & 63;
    const int lr = l & 15;
    const int kg = l >> 4;
    const int n0 = blockIdx.x * 32;
    const int s  = blockIdx.y;

    const int mstart = s * ksplit;
    const int nch    = ksplit >> 5;
    const int coff   = blockIdx.x & (nch - 1);
#define PCH(c) ((((c) + coff) & (nch - 1)))
#define CLC(c) ((c) < nch ? (c) : nch - 1)

    const _Float16 es0 = Es[h * NN + n0 + lr],      fs0 = Fs[h * NN + n0 + lr];
    const _Float16 es1 = Es[h * NN + n0 + 16 + lr], fs1 = Fs[h * NN + n0 + 16 + lr];
    const f16x2 es20 = {es0, es0}, fs20 = {fs0, fs0};
    const f16x2 es21 = {es1, es1}, fs21 = {fs1, fs1};

    const _Float16* __restrict__ EnB = En + (size_t)h * NN + mstart + kg * 8;
    const _Float16* __restrict__ FnB = Fn + (size_t)h * NN + mstart + kg * 8;
    const _Float16* __restrict__ bhead =
        Bpack + ((size_t)(h * 128) + (mstart >> 5)) * 2048 + l * 8;

    // staging: thread t -> row sr, quad mq (4 ints); swizzled LDS f16 offset
    const int sr = t >> 3;
    const int mq = t & 7;
    const int swoff = sr * 32 + (((mq >> 1) ^ (sr & 3)) << 3) + (mq & 1) * 4;
    const int* __restrict__ adjRow = adj + (size_t)(n0 + sr) * NN + mstart;

    // A-side LDS read offsets (granule swizzle; (lr+16)&3 == lr&3)
    const int perm = kg ^ (lr & 3);
    const int ro0  = lr * 32 + perm * 8;
    const int ro1  = (lr + 16) * 32 + perm * 8;

    f32x4 acc[2][4] = {};
    f32x4 dacc[2]   = {};
    f16x8 ones;
    #pragma unroll
    for (int j = 0; j < 8; ++j) ones[j] = (_Float16)1.0f;

    union U8 { f16x8 v; unsigned int u[4]; };

#define LDADJ(DST, C) do {                                                    \
        DST = ((const int4*)(adjRow + PCH(CLC(C)) * 32))[mq];                 \
    } while (0)
#define STADJ(PB, SUB, SRC) do {                                              \
        f16x4 _hv = {(_Float16)(SRC.x != 0), (_Float16)(SRC.y != 0),          \
                     (_Float16)(SRC.z != 0), (_Float16)(SRC.w != 0)};         \
        *(f16x4*)&adjh[PB][SUB][swoff] = _hv;                                 \
    } while (0)
#define LOADB(DST, C) do {                                                    \
        const _Float16* _b = bhead + (size_t)PCH(CLC(C)) * 2048;              \
        _Pragma("unroll")                                                     \
        for (int _cb = 0; _cb < 4; ++_cb)                                     \
            DST[_cb] = *(const f16x8*)(_b + _cb * 512);                       \
    } while (0)
#define LOADT(EQ, FQ, C) do {                                                 \
        EQ = *(const uint4*)(EnB + PCH(CLC(C)) * 32);                         \
        FQ = *(const uint4*)(FnB + PCH(CLC(C)) * 32);                         \
    } while (0)

#define CHUNK(C, PB, SUB, BCUR, BNXT, EQC, FQC, EQN, FQN) do {                \
        LOADB(BNXT, (C) + 1);                                                 \
        LOADT(EQN, FQN, (C) + 1);                                             \
        U8 AM0, AM1;                                                          \
        AM0.v = *(const f16x8*)&adjh[PB][SUB][ro0];                           \
        AM1.v = *(const f16x8*)&adjh[PB][SUB][ro1];                           \
        U8 A0, A1;                                                            \
        _Pragma("unroll")                                                     \
        for (int p = 0; p < 4; ++p) {                                         \
            const unsigned int eu = p == 0 ? EQC.x : p == 1 ? EQC.y : p == 2 ? EQC.z : EQC.w; \
            const unsigned int fu = p == 0 ? FQC.x : p == 1 ? FQC.y : p == 2 ? FQC.z : FQC.w; \
            const f16x2 en2 = __builtin_bit_cast(f16x2, eu);                  \
            const f16x2 fn2 = __builtin_bit_cast(f16x2, fu);                  \
            const f16x2 a20 = __builtin_bit_cast(f16x2, AM0.u[p]);            \
            const f16x2 a21 = __builtin_bit_cast(f16x2, AM1.u[p]);            \
            const f16x2 v0 = __builtin_elementwise_max(es20 * en2, fs20 * fn2) * a20; \
            const f16x2 v1 = __builtin_elementwise_max(es21 * en2, fs21 * fn2) * a21; \
            A0.u[p] = __builtin_bit_cast(unsigned int, v0);                   \
            A1.u[p] = __builtin_bit_cast(unsigned int, v1);                   \
        }                                                                     \
        __builtin_amdgcn_s_setprio(1);                                        \
        _Pragma("unroll")                                                     \
        for (int _cb = 0; _cb < 4; ++_cb) {                                   \
            acc[0][_cb] = __builtin_amdgcn_mfma_f32_16x16x32_f16(A0.v, BCUR[_cb], acc[0][_cb], 0, 0, 0); \
            acc[1][_cb] = __builtin_amdgcn_mfma_f32_16x16x32_f16(A1.v, BCUR[_cb], acc[1][_cb], 0, 0, 0); \
        }                                                                     \
        dacc[0] = __builtin_amdgcn_mfma_f32_16x16x32_f16(A0.v, ones, dacc[0], 0, 0, 0); \
        dacc[1] = __builtin_amdgcn_mfma_f32_16x16x32_f16(A1.v, ones, dacc[1], 0, 0, 0); \
        __builtin_amdgcn_s_setprio(0);                                        \
    } while (0)

    f16x8 B_0[4], B_1[4];
    uint4 eq0, fq0, eq1, fq1;
    int4  aA, aB;

    // ---- prologue: pair 0 -> buf0; regs <- pair 1; B/tables for chunk 0 ----
    LDADJ(aA, 0);
    LDADJ(aB, 1);
    STADJ(0, 0, aA);
    STADJ(0, 1, aB);
    LDADJ(aA, 2);
    LDADJ(aB, 3);
    LOADB(B_0, 0);
    LOADT(eq0, fq0, 0);
    LDS_BARRIER();

    const int npair = nch >> 1;
    for (int k = 0; k < npair; ++k) {
        const int nb = (k + 1) & 1;
        const int pb = k & 1;
        // stage pair k+1 (regs loaded at pair k-1), prefetch pair k+2
        STADJ(nb, 0, aA);
        STADJ(nb, 1, aB);
        LDADJ(aA, 2 * k + 4);
        LDADJ(aB, 2 * k + 5);

        CHUNK(2 * k,     pb, 0, B_0, B_1, eq0, fq0, eq1, fq1);
        CHUNK(2 * k + 1, pb, 1, B_1, B_0, eq1, fq1, eq0, fq0);

        LDS_BARRIER();   // lgkm-only: pair k+2 adj loads stay in flight
    }
#undef CHUNK
#undef LOADT
#undef LOADB
#undef STADJ
#undef LDADJ
#undef CLC
#undef PCH

    #pragma unroll
    for (int rb = 0; rb < 2; ++rb) {
        #pragma unroll
        for (int r = 0; r < 4; ++r) {
            const int row = n0 + rb * 16 + kg * 4 + r;
            #pragma unroll
            for (int cb = 0; cb < 4; ++cb)
                pacc[((size_t)(s * NN + row)) * NC + h * 64 + cb * 16 + lr] =
                    (_Float16)acc[rb][cb][r];
            if (lr == 0)
                pden[(s * NN + row) * 4 + h] = (_Float16)dacc[rb][r];
        }
    }
}

// ---------------------------------------------------------------------------
// Kernel 3: reduce f16 splits in f32, normalize, ReLU. 8 rows/block.
// ---------------------------------------------------------------------------
__global__ __launch_bounds__(256) void finalize_kernel(
    const _Float16* __restrict__ pacc, const _Float16* __restrict__ pden,
    float* __restrict__ out, int nsplit)
{
    const int t = threadIdx.x;
    const int n = blockIdx.x * 8 + (t >> 5);
    const int q = t & 31;              // 8-col group
    const int h = q >> 3;

    float a[8];
    #pragma unroll
    for (int i = 0; i < 8; ++i) a[i] = 0.f;
    float d = 0.f;
    for (int s = 0; s < nsplit; ++s) {
        const f16x8 v = *(const f16x8*)&pacc[((size_t)(s * NN + n)) * NC + q * 8];
        #pragma unroll
        for (int i = 0; i < 8; ++i) a[i] += (float)v[i];
        d += (float)pden[(s * NN + n) * 4 + h];
    }
    const float inv = (d > 0.f) ? 1.0f / d : 0.f;
    f32x4 o0, o1;
    #pragma unroll
    for (int i = 0; i < 4; ++i) {
        const float v0 = a[i] * inv;
        const float v1 = a[i + 4] * inv;
        o0[i] = v0 > 0.f ? v0 : 0.f;
        o1[i] = v1 > 0.f ? v1 : 0.f;
    }
    float* po = &out[(size_t)n * NC + q * 8];
    *(f32x4*)po       = o0;
    *(f32x4*)(po + 4) = o1;
}

// ---------------------------------------------------------------------------
extern "C" void kernel_launch(void* const* d_in, const int* in_sizes, int n_in,
                              void* d_out, int out_size, void* d_ws, size_t ws_size,
                              hipStream_t stream)
{
    const int*   adj   = (const int*)d_in[0];
    const float* feats = (const float*)d_in[1];
    const float* W     = (const float*)d_in[2];
    const float* ak    = (const float*)d_in[3];
    float*       out   = (float*)d_out;

    char* ws = (char*)d_ws;
    _Float16* Bpack = (_Float16*)ws;                                  // 2 MB
    _Float16* Es    = (_Float16*)(ws + (2ull << 20));                 // 32 KB
    _Float16* Fs    = (_Float16*)(ws + (2ull << 20) + (1 << 15));     // 32 KB
    _Float16* En    = (_Float16*)(ws + (2ull << 20) + (2 << 15));     // 32 KB
    _Float16* Fn    = (_Float16*)(ws + (2ull << 20) + (3 << 15));     // 32 KB
    _Float16* pden  = (_Float16*)(ws + (2ull << 20) + (4 << 15));     // <=512 KB
    _Float16* pacc  = (_Float16*)(ws + (3ull << 20));                 // nsplit*2 MB

    int nsplit = 16;
    while (nsplit > 1 && ws_size < (3ull << 20) + (size_t)nsplit * (2ull << 20))
        nsplit >>= 1;
    const int ksplit = NN / nsplit;

    prep_kernel<<<dim3(128, 4), 256, 0, stream>>>(feats, W, ak, Bpack, Es, Fs, En, Fn);
    attn_kernel<<<dim3(128, nsplit), 256, 0, stream>>>(adj, Bpack, Es, Fs, En, Fn,
                                                       pacc, pden, ksplit);
    finalize_kernel<<<512, 256, 0, stream>>>(pacc, pden, out, nsplit);
}